// Round 1
// baseline (381.145 us; speedup 1.0000x reference)
//
#include <hip/hip_runtime.h>

// IFOPooling: h_t = f_t * h_{t-1} + i_t * z_t along S (contiguous axis).
// Layout [B=16, H=1024, S=2048] fp32. One block per (b,h) row; work-efficient
// linear-recurrence scan: per-thread serial chunk -> wave shuffle scan ->
// cross-wave LDS scan -> replay. All inputs held in registers between passes.

constexpr int S_LEN = 2048;
constexpr int TPB   = 512;   // 8 waves; 4 elements (one float4) per thread

__global__ __launch_bounds__(TPB) void ifo_scan_kernel(
    const float* __restrict__ f,
    const float* __restrict__ z,
    const float* __restrict__ iin,
    float* __restrict__ out)
{
    const size_t base = (size_t)blockIdx.x * S_LEN;
    const int t    = threadIdx.x;
    const int lane = t & 63;
    const int wave = t >> 6;

    const float4 ff = reinterpret_cast<const float4*>(f   + base)[t];
    const float4 zz = reinterpret_cast<const float4*>(z   + base)[t];
    const float4 ii = reinterpret_cast<const float4*>(iin + base)[t];

    float4 xx;
    xx.x = ii.x * zz.x;
    xx.y = ii.y * zz.y;
    xx.z = ii.z * zz.z;
    xx.w = ii.w * zz.w;

    // Local chunk composition: h_out = A*h_in + B
    float A = ff.x, B = xx.x;
    A = ff.y * A;  B = ff.y * B + xx.y;
    A = ff.z * A;  B = ff.z * B + xx.z;
    A = ff.w * A;  B = ff.w * B + xx.w;

    // Wave-level inclusive scan of (A,B) under composition
    float a = A, b = B;
    #pragma unroll
    for (int d = 1; d < 64; d <<= 1) {
        float a_up = __shfl_up(a, d);
        float b_up = __shfl_up(b, d);
        if (lane >= d) {
            b = a * b_up + b;   // apply current after previous
            a = a * a_up;
        }
    }

    // Cross-wave scan (8 waves) via LDS
    __shared__ float wa[8], wb[8];
    if (lane == 63) { wa[wave] = a; wb[wave] = b; }
    __syncthreads();

    float pa = 1.0f, pb = 0.0f;          // exclusive prefix over earlier waves
    for (int w = 0; w < wave; ++w) {
        pb = wa[w] * pb + wb[w];
        pa = wa[w] * pa;
    }

    // Exclusive within-wave composition (shift inclusive up by one lane)
    float ea = __shfl_up(a, 1);
    float eb = __shfl_up(b, 1);
    if (lane == 0) { ea = 1.0f; eb = 0.0f; }

    // h entering this thread's chunk (h_{-1} = 0 -> only b-part matters)
    float h = ea * pb + eb;
    (void)pa;

    // Replay chunk with carried h; store
    float4 oo;
    h = ff.x * h + xx.x;  oo.x = h;
    h = ff.y * h + xx.y;  oo.y = h;
    h = ff.z * h + xx.z;  oo.z = h;
    h = ff.w * h + xx.w;  oo.w = h;
    reinterpret_cast<float4*>(out + base)[t] = oo;
}

extern "C" void kernel_launch(void* const* d_in, const int* in_sizes, int n_in,
                              void* d_out, int out_size, void* d_ws, size_t ws_size,
                              hipStream_t stream) {
    const float* f = (const float*)d_in[0];
    const float* z = (const float*)d_in[1];
    const float* i = (const float*)d_in[2];
    float* out = (float*)d_out;

    const int rows = out_size / S_LEN;   // B*H = 16384
    ifo_scan_kernel<<<rows, TPB, 0, stream>>>(f, z, i, out);
}